// Round 3
// baseline (472.461 us; speedup 1.0000x reference)
//
#include <hip/hip_runtime.h>
#include <math.h>

// Problem constants (MoEGate: B=4,T=4096,C=2048,E=64,K=8)
#define NTOK  16384
#define CDIM  2048
#define NEXP  64
#define TOPK  8

// ============================================================================
// Scheme C GEMM: lane = token, register = expert. No LDS, no barriers.
// Wave = 64 tokens x 64 experts over a k-slice of CDIM/KS.
//   - x: per-lane row loads (float4; each lane consumes its own 64B lines)
//   - W: wave-uniform indices -> scalar loads (SMEM pipe), v_fmac v,s,v
//   - acc[64] VGPRs per lane; partials out coalesced as part[pp][e][t]
// ============================================================================
template<int KS>
__global__ __launch_bounds__(256, 4) void gemm_rowwave_kernel(
    const float* __restrict__ x,      // [NTOK][CDIM]
    const float* __restrict__ W,      // [NEXP][CDIM]
    float*       __restrict__ part)   // [KS][NEXP][NTOK]
{
    const int SL   = CDIM / KS;            // k-slice per block
    const int tb   = blockIdx.x & 63;      // token block (256 tokens)
    const int pp   = blockIdx.x >> 6;      // k-split part
    const int lane = threadIdx.x & 63;
    const int wid  = threadIdx.x >> 6;
    const int tok  = tb * 256 + wid * 64 + lane;
    const int k0   = pp * SL;

    float acc[NEXP];
    #pragma unroll
    for (int e = 0; e < NEXP; e++) acc[e] = 0.f;

    const float* xrow = x + (size_t)tok * CDIM + k0;

    for (int kc = 0; kc < SL; kc += 16) {
        float xr[16];
        #pragma unroll
        for (int q = 0; q < 4; q++) {
            float4 v = *(const float4*)&xrow[kc + q * 4];
            xr[q*4+0] = v.x; xr[q*4+1] = v.y; xr[q*4+2] = v.z; xr[q*4+3] = v.w;
        }
        const float* wp = W + k0 + kc;     // wave-uniform
        #pragma unroll
        for (int e = 0; e < NEXP; e++) {
            const float* we = wp + (size_t)e * CDIM;   // uniform -> s_load
            #pragma unroll
            for (int j = 0; j < 16; j++)
                acc[e] = fmaf(xr[j], we[j], acc[e]);
        }
    }

    float* dst = part + (size_t)pp * NEXP * NTOK + tok;
    #pragma unroll
    for (int e = 0; e < NEXP; e++)
        dst[(size_t)e * NTOK] = acc[e];    // lanes consecutive: coalesced
}

// ============================================================================
// Reduce partials + top-8 + sigmoid + normalize + masked counts.
// Block = 256 threads / 64 tokens. Waves split the KS partials, LDS-combine;
// wave 0 does fully in-register top-8 per lane (lane = token).
// ============================================================================
template<int KS>
__global__ __launch_bounds__(256) void reduce_topk_kernel(
    const float* __restrict__ part,    // [KS][NEXP][NTOK]
    const int*   __restrict__ mask,    // [NTOK]
    const float* __restrict__ gbias,   // [NEXP]
    const float* __restrict__ ebias,   // [NEXP]
    float*       __restrict__ out,     // [2*NTOK*TOPK + 1]
    unsigned int* __restrict__ counts) // [NEXP]
{
    __shared__ float Ls[4][NEXP][64];
    __shared__ unsigned int s_cnt[NEXP];
    const int lane = threadIdx.x & 63;
    const int wid  = threadIdx.x >> 6;
    const int t    = blockIdx.x * 64 + lane;
    if (threadIdx.x < NEXP) s_cnt[threadIdx.x] = 0u;

    const int PPW = KS / 4;                // partials per wave
    float s[NEXP];
    #pragma unroll
    for (int e = 0; e < NEXP; e++) s[e] = 0.f;
    for (int p = 0; p < PPW; p++) {
        const float* src = part + (size_t)(wid * PPW + p) * NEXP * NTOK + t;
        #pragma unroll
        for (int e = 0; e < NEXP; e++)
            s[e] += src[(size_t)e * NTOK];
    }
    #pragma unroll
    for (int e = 0; e < NEXP; e++) Ls[wid][e][lane] = s[e];
    __syncthreads();

    if (wid == 0) {
        float z[NEXP];
        #pragma unroll
        for (int e = 0; e < NEXP; e++)
            z[e] = Ls[0][e][lane] + Ls[1][e][lane] + Ls[2][e][lane]
                 + Ls[3][e][lane] + gbias[e];

        unsigned long long used = 0ull;
        int idxs[TOPK]; float probs[TOPK]; float psum = 0.f;
        #pragma unroll
        for (int r = 0; r < TOPK; r++) {
            float bv = -INFINITY, bz = 0.f; int bi = 0;
            #pragma unroll
            for (int e = 0; e < NEXP; e++) {
                float v = ((used >> e) & 1ull) ? -INFINITY : (z[e] + ebias[e]);
                if (v > bv) { bv = v; bz = z[e]; bi = e; }  // strict >: lowest idx wins ties
            }
            used |= (1ull << bi);
            idxs[r] = bi;
            float p = 1.f / (1.f + expf(-bz));
            probs[r] = p; psum += p;
        }
        float inv = 1.f / psum;
        #pragma unroll
        for (int r = 0; r < TOPK; r++) {
            out[(size_t)t * TOPK + r] = (float)idxs[r];
            out[(size_t)NTOK * TOPK + (size_t)t * TOPK + r] = probs[r] * inv;
        }
        if (mask[t] != 0) {
            #pragma unroll
            for (int r = 0; r < TOPK; r++) atomicAdd(&s_cnt[idxs[r]], 1u);
        }
        // wave 0 is the only writer; program order + compiler waitcnt make
        // the per-lane flush below safe without a barrier.
        atomicAdd(&counts[lane], s_cnt[lane]);
    }
}

__global__ void finalize_kernel(const unsigned int* __restrict__ counts,
                                float* __restrict__ out)
{
    const int t = threadIdx.x;   // 64 threads, one wave
    float c  = (float)counts[t];
    float mx = c, sm = c;
    #pragma unroll
    for (int o = 32; o > 0; o >>= 1) {
        mx = fmaxf(mx, __shfl_down(mx, o));
        sm += __shfl_down(sm, o);
    }
    if (t == 0) {
        float avg = sm / (float)NEXP;
        out[2 * NTOK * TOPK] = (mx - avg) / (avg + 1e-5f);
    }
}

// ============================================================================
// R2 pipeline kept as fallback for small workspace.
// ============================================================================
__global__ __launch_bounds__(256) void pack_w_kernel(
    const float* __restrict__ W, float* __restrict__ Wp)
{
    int lin = blockIdx.x * 256 + threadIdx.x;
    int tx = lin & 15;
    int j  = (lin >> 4) & 3;
    int kc = (lin >> 6) & 7;
    int kt = lin >> 9;
    float4 v = *(const float4*)&W[(size_t)(tx * 4 + j) * CDIM + kt * 32 + kc * 4];
    *(float4*)&Wp[(size_t)lin * 4] = v;
}

template<int KS>
__global__ __launch_bounds__(256) void gemm_partial_kernel(
    const float* __restrict__ x, const float* __restrict__ Wp,
    float* __restrict__ part)   // [KS][NTOK][NEXP]
{
    __shared__ float As[64][36];
    __shared__ float Bs[2048];
    const int tid = threadIdx.x;
    const int tx  = tid & 15;
    const int ty  = tid >> 4;
    const int bm  = blockIdx.x & 255;
    const int pp  = blockIdx.x >> 8;
    const int TILES = 64 / KS;
    const int kt0 = pp * TILES;
    const int m0  = bm * 64;
    float acc[4][4] = {};
    for (int tt = 0; tt < TILES; tt++) {
        const int kb = (kt0 + tt) * 32;
        __syncthreads();
        #pragma unroll
        for (int p = 0; p < 2; p++) {
            int lin = tid + p * 256;
            int m   = lin >> 3;
            int c4  = (lin & 7) << 2;
            *(float4*)&As[m][c4] = *(const float4*)&x[(size_t)(m0 + m) * CDIM + kb + c4];
        }
        const float* wsrc = Wp + (size_t)(kt0 + tt) * 2048;
        #pragma unroll
        for (int p = 0; p < 2; p++) {
            int lin = tid + p * 256;
            *(float4*)&Bs[lin * 4] = *(const float4*)&wsrc[lin * 4];
        }
        __syncthreads();
        #pragma unroll
        for (int kc = 0; kc < 8; kc++) {
            float4 a[4], b[4];
            #pragma unroll
            for (int i = 0; i < 4; i++) a[i] = *(const float4*)&As[ty * 4 + i][kc * 4];
            #pragma unroll
            for (int j = 0; j < 4; j++) b[j] = *(const float4*)&Bs[((kc * 4 + j) * 16 + tx) * 4];
            #pragma unroll
            for (int i = 0; i < 4; i++)
                #pragma unroll
                for (int j = 0; j < 4; j++)
                    acc[i][j] += a[i].x * b[j].x + a[i].y * b[j].y
                               + a[i].z * b[j].z + a[i].w * b[j].w;
        }
    }
    float* dst = part + ((size_t)pp * NTOK + m0) * NEXP;
    #pragma unroll
    for (int i = 0; i < 4; i++) {
        float4 v = make_float4(acc[i][0], acc[i][1], acc[i][2], acc[i][3]);
        *(float4*)&dst[(size_t)(ty * 4 + i) * NEXP + tx * 4] = v;
    }
}

template<int KS>
__global__ __launch_bounds__(256) void topk_kernel(
    const float* __restrict__ part, const int* __restrict__ mask,
    const float* __restrict__ gbias, const float* __restrict__ ebias,
    float* __restrict__ out, unsigned int* __restrict__ counts)
{
    __shared__ unsigned int s_cnt[NEXP];
    const int tid = threadIdx.x;
    if (tid < NEXP) s_cnt[tid] = 0u;
    __syncthreads();
    const int t = blockIdx.x * 16 + (tid >> 4);
    const int l = tid & 15;
    float4 v = make_float4(0.f, 0.f, 0.f, 0.f);
    #pragma unroll
    for (int p = 0; p < KS; p++) {
        float4 u = *(const float4*)&part[((size_t)p * NTOK + t) * NEXP + l * 4];
        v.x += u.x; v.y += u.y; v.z += u.z; v.w += u.w;
    }
    float4 gb = *(const float4*)&gbias[l * 4];
    float4 eb = *(const float4*)&ebias[l * 4];
    float z[4], sel[4];
    z[0] = v.x + gb.x; z[1] = v.y + gb.y; z[2] = v.z + gb.z; z[3] = v.w + gb.w;
    sel[0] = z[0] + eb.x; sel[1] = z[1] + eb.y; sel[2] = z[2] + eb.z; sel[3] = z[3] + eb.w;
    int idxs[TOPK]; float probs[TOPK]; float psum = 0.f;
    #pragma unroll
    for (int r = 0; r < TOPK; r++) {
        float bv = -INFINITY, bz = 0.f; int bidx = 1 << 30;
        #pragma unroll
        for (int i = 0; i < 4; i++)
            if (sel[i] > bv) { bv = sel[i]; bz = z[i]; bidx = l * 4 + i; }
        #pragma unroll
        for (int m = 1; m < 16; m <<= 1) {
            float ov = __shfl_xor(bv, m);
            float oz = __shfl_xor(bz, m);
            int   oi = __shfl_xor(bidx, m);
            if (ov > bv || (ov == bv && oi < bidx)) { bv = ov; bz = oz; bidx = oi; }
        }
        idxs[r] = bidx;
        float p = 1.f / (1.f + expf(-bz));
        probs[r] = p; psum += p;
        if ((bidx >> 2) == l) sel[bidx & 3] = -INFINITY;
    }
    float inv = 1.f / psum;
    if (l < TOPK) {
        out[(size_t)t * TOPK + l] = (float)idxs[l];
        out[(size_t)NTOK * TOPK + (size_t)t * TOPK + l] = probs[l] * inv;
        if (mask[t] != 0) atomicAdd(&s_cnt[idxs[l]], 1u);
    }
    __syncthreads();
    if (tid < NEXP && s_cnt[tid] != 0u) atomicAdd(&counts[tid], s_cnt[tid]);
}

__global__ __launch_bounds__(256) void fused_fallback_kernel(
    const float* __restrict__ x, const int* __restrict__ mask,
    const float* __restrict__ W, const float* __restrict__ gbias,
    const float* __restrict__ ebias, float* __restrict__ out,
    unsigned int* __restrict__ counts)
{
    __shared__ float As[64][36];
    __shared__ float Bs[64][36];
    __shared__ float Lg[64][NEXP + 1];
    __shared__ float s_gb[NEXP], s_eb[NEXP];
    __shared__ unsigned int s_cnt[NEXP];
    const int tid = threadIdx.x;
    const int tx = tid & 15, ty = tid >> 4;
    const int m0 = blockIdx.x * 64;
    if (tid < NEXP) { s_gb[tid] = gbias[tid]; s_eb[tid] = ebias[tid]; s_cnt[tid] = 0u; }
    float acc[4][4] = {};
    for (int kb = 0; kb < CDIM; kb += 32) {
        __syncthreads();
        #pragma unroll
        for (int p = 0; p < 2; p++) {
            int lin = tid + p * 256; int m = lin >> 3; int c4 = (lin & 7) << 2;
            *(float4*)&As[m][c4] = *(const float4*)&x[(size_t)(m0 + m) * CDIM + kb + c4];
            *(float4*)&Bs[m][c4] = *(const float4*)&W[(size_t)m * CDIM + kb + c4];
        }
        __syncthreads();
        #pragma unroll
        for (int k4 = 0; k4 < 32; k4 += 4) {
            float4 a[4], b[4];
            #pragma unroll
            for (int i = 0; i < 4; i++) a[i] = *(const float4*)&As[ty * 4 + i][k4];
            #pragma unroll
            for (int j = 0; j < 4; j++) b[j] = *(const float4*)&Bs[tx * 4 + j][k4];
            #pragma unroll
            for (int i = 0; i < 4; i++)
                #pragma unroll
                for (int j = 0; j < 4; j++)
                    acc[i][j] += a[i].x * b[j].x + a[i].y * b[j].y
                               + a[i].z * b[j].z + a[i].w * b[j].w;
        }
    }
    __syncthreads();
    #pragma unroll
    for (int i = 0; i < 4; i++)
        #pragma unroll
        for (int j = 0; j < 4; j++)
            Lg[ty * 4 + i][tx * 4 + j] = acc[i][j] + s_gb[tx * 4 + j];
    __syncthreads();
    if (tid < 64) {
        const int g = m0 + tid;
        unsigned long long used = 0ull;
        int idxs[TOPK]; float probs[TOPK]; float psum = 0.f;
        #pragma unroll
        for (int k = 0; k < TOPK; k++) {
            float best = -INFINITY; int bi = 0;
            for (int n = 0; n < NEXP; n++) {
                if ((used >> n) & 1ull) continue;
                float vv = Lg[tid][n] + s_eb[n];
                if (vv > best) { best = vv; bi = n; }
            }
            used |= (1ull << bi);
            idxs[k] = bi;
            float p = 1.f / (1.f + expf(-Lg[tid][bi]));
            probs[k] = p; psum += p;
        }
        float inv = 1.f / psum;
        #pragma unroll
        for (int k = 0; k < TOPK; k++) {
            out[(size_t)g * TOPK + k] = (float)idxs[k];
            out[(size_t)NTOK * TOPK + (size_t)g * TOPK + k] = probs[k] * inv;
        }
        if (mask[g] != 0)
            #pragma unroll
            for (int k = 0; k < TOPK; k++) atomicAdd(&s_cnt[idxs[k]], 1u);
    }
    __syncthreads();
    if (tid < NEXP && s_cnt[tid] != 0u) atomicAdd(&counts[tid], s_cnt[tid]);
}

extern "C" void kernel_launch(void* const* d_in, const int* in_sizes, int n_in,
                              void* d_out, int out_size, void* d_ws, size_t ws_size,
                              hipStream_t stream)
{
    const float* x     = (const float*)d_in[0];
    const int*   mask  = (const int*)  d_in[1];
    const float* W     = (const float*)d_in[2];
    const float* gbias = (const float*)d_in[3];
    const float* ebias = (const float*)d_in[4];
    float* out = (float*)d_out;

    unsigned int* counts = (unsigned int*)d_ws;
    float* part = (float*)((char*)d_ws + 256);

    const size_t partB1 = (size_t)NTOK * NEXP * sizeof(float);   // 4 MB
    const size_t wpB    = (size_t)NEXP * CDIM * sizeof(float);   // 512 KB
    auto needC = [&](int ks) { return 256 + (size_t)ks * partB1; };
    auto needR2 = [&](int ks) { return 256 + (size_t)ks * partB1 + wpB; };

    hipMemsetAsync(d_ws, 0, 256, stream);

    if (ws_size >= needC(16)) {
        gemm_rowwave_kernel<16><<<64 * 16, 256, 0, stream>>>(x, W, part);
        reduce_topk_kernel<16><<<NTOK / 64, 256, 0, stream>>>(part, mask, gbias, ebias, out, counts);
        finalize_kernel<<<1, 64, 0, stream>>>(counts, out);
        return;
    }
    if (ws_size >= needC(8)) {
        gemm_rowwave_kernel<8><<<64 * 8, 256, 0, stream>>>(x, W, part);
        reduce_topk_kernel<8><<<NTOK / 64, 256, 0, stream>>>(part, mask, gbias, ebias, out, counts);
        finalize_kernel<<<1, 64, 0, stream>>>(counts, out);
        return;
    }

    // R2 fallback pipeline
    int KS = 0;
    if      (ws_size >= needR2(4)) KS = 4;
    else if (ws_size >= needR2(2)) KS = 2;
    else if (ws_size >= needR2(1)) KS = 1;

    if (KS == 0) {
        fused_fallback_kernel<<<NTOK / 64, 256, 0, stream>>>(x, mask, W, gbias, ebias, out, counts);
        finalize_kernel<<<1, 64, 0, stream>>>(counts, out);
        return;
    }

    float* Wp = (float*)((char*)d_ws + 256 + (size_t)KS * partB1);
    pack_w_kernel<<<128, 256, 0, stream>>>(W, Wp);
    if (KS == 4) {
        gemm_partial_kernel<4><<<256 * 4, 256, 0, stream>>>(x, Wp, part);
        topk_kernel<4><<<NTOK / 16, 256, 0, stream>>>(part, mask, gbias, ebias, out, counts);
    } else if (KS == 2) {
        gemm_partial_kernel<2><<<256 * 2, 256, 0, stream>>>(x, Wp, part);
        topk_kernel<2><<<NTOK / 16, 256, 0, stream>>>(part, mask, gbias, ebias, out, counts);
    } else {
        gemm_partial_kernel<1><<<256 * 1, 256, 0, stream>>>(x, Wp, part);
        topk_kernel<1><<<NTOK / 16, 256, 0, stream>>>(part, mask, gbias, ebias, out, counts);
    }
    finalize_kernel<<<1, 64, 0, stream>>>(counts, out);
}

// Round 4
// 231.035 us; speedup vs baseline: 2.0450x; 2.0450x over previous
//
#include <hip/hip_runtime.h>
#include <math.h>

// Problem constants (MoEGate: B=4,T=4096,C=2048,E=64,K=8)
#define NTOK   16384
#define CDIM   2048
#define NEXP   64
#define TOPK   8
#define KSPLIT 4

typedef _Float16 f16x8 __attribute__((ext_vector_type(8)));
typedef float    f32x4 __attribute__((ext_vector_type(4)));

// ============================================================================
// Kernel 1: pack W[64][2048] fp32 into f16 hi/lo images in MFMA B-fragment
// order. Entry t = ((s*4 + nt)*64 + lane): 8 f16 for (expert = nt*16+(lane&15),
// k = s*32 + (lane>>4)*8 + j). GEMM lane then loads one contiguous 16B chunk.
// ============================================================================
__global__ __launch_bounds__(256) void pack_w16_kernel(
    const float* __restrict__ W,
    _Float16* __restrict__ Wh, _Float16* __restrict__ Wl)
{
    int t    = blockIdx.x * 256 + threadIdx.x;   // 0..16383
    int lane = t & 63;
    int nt   = (t >> 6) & 3;
    int s    = t >> 8;                           // k32-step, 0..63
    int e    = nt * 16 + (lane & 15);
    int k    = s * 32 + (lane >> 4) * 8;
    const float* src = W + (size_t)e * CDIM + k;
    #pragma unroll
    for (int j = 0; j < 8; j++) {
        float x = src[j];
        _Float16 h = (_Float16)x;                // rte
        Wh[(size_t)t * 8 + j] = h;
        Wl[(size_t)t * 8 + j] = (_Float16)(x - (float)h);
    }
}

// ============================================================================
// Kernel 2: f16-split MFMA GEMM. Wave = 16 tokens x 64 experts over a k-slice
// of 512 (KSPLIT=4). A-frags loaded directly from global (lines fully
// consumed), split to f16 hi/lo in-register; B-frags from packed images
// (L2-hot). 3 MFMAs per (k32, n-tile): hh + lh + hl; ll dropped (~2^-22).
// No LDS, no barriers. fp32 partials to part[pp][tok][e].
// ============================================================================
__global__ __launch_bounds__(256, 4) void gemm_f16split_kernel(
    const float* __restrict__ x,       // [NTOK][CDIM]
    const _Float16* __restrict__ Wh,   // packed image, 256 KB
    const _Float16* __restrict__ Wl,   // packed image, 256 KB
    float* __restrict__ part)          // [KSPLIT][NTOK][NEXP]
{
    const int lane = threadIdx.x & 63;
    const int wid  = threadIdx.x >> 6;
    const int tb   = blockIdx.x & 255;           // token block (64 tokens)
    const int pp   = blockIdx.x >> 8;            // k-split part
    const int tok0 = tb * 64 + wid * 16;
    const int q    = lane >> 4;                  // quad
    const size_t xbase = (size_t)(tok0 + (lane & 15)) * CDIM + pp * 512 + q * 8;

    f32x4 acc[4];
    #pragma unroll
    for (int nt = 0; nt < 4; nt++) acc[nt] = (f32x4){0.f, 0.f, 0.f, 0.f};

    for (int s = 0; s < 16; s++) {
        const int S = pp * 16 + s;               // absolute k32-step
        float4 v0 = *(const float4*)&x[xbase + s * 32];
        float4 v1 = *(const float4*)&x[xbase + s * 32 + 4];
        float xr[8] = {v0.x, v0.y, v0.z, v0.w, v1.x, v1.y, v1.z, v1.w};
        f16x8 ah, al;
        #pragma unroll
        for (int j = 0; j < 8; j++) {
            _Float16 h = (_Float16)xr[j];
            ah[j] = h;
            al[j] = (_Float16)(xr[j] - (float)h);   // exact residual (Sterbenz)
        }
        const f16x8* bhp = (const f16x8*)(Wh + ((size_t)S * 4 * 64 + lane) * 8);
        const f16x8* blp = (const f16x8*)(Wl + ((size_t)S * 4 * 64 + lane) * 8);
        #pragma unroll
        for (int nt = 0; nt < 4; nt++) {
            f16x8 bh = bhp[nt * 64];
            f16x8 bl = blp[nt * 64];
            acc[nt] = __builtin_amdgcn_mfma_f32_16x16x32_f16(ah, bh, acc[nt], 0, 0, 0);
            acc[nt] = __builtin_amdgcn_mfma_f32_16x16x32_f16(al, bh, acc[nt], 0, 0, 0);
            acc[nt] = __builtin_amdgcn_mfma_f32_16x16x32_f16(ah, bl, acc[nt], 0, 0, 0);
        }
    }

    // D layout: token = tok0 + q*4 + r, expert = nt*16 + (lane&15)
    #pragma unroll
    for (int nt = 0; nt < 4; nt++) {
        #pragma unroll
        for (int r = 0; r < 4; r++) {
            size_t tok = (size_t)tok0 + q * 4 + r;
            part[((size_t)pp * NTOK + tok) * NEXP + nt * 16 + (lane & 15)] = acc[nt][r];
        }
    }
}

// ============================================================================
// Kernel 3: sum k-split partials + gate_bias, top-8 (strict >, lowest index
// wins ties = JAX), sigmoid, normalize, per-block masked counts (LDS atomics
// only; per-block counts to blockcnt — ZERO global atomics).
// Block = 1 wave = 64 tokens; grid = 256.
// ============================================================================
__global__ __launch_bounds__(64) void reduce_topk_kernel(
    const float* __restrict__ part,     // [KSPLIT][NTOK][NEXP]
    const int*   __restrict__ mask,     // [NTOK]
    const float* __restrict__ gbias,    // [NEXP]
    const float* __restrict__ ebias,    // [NEXP]
    float*       __restrict__ out,      // [2*NTOK*TOPK + 1]
    float*       __restrict__ blockcnt) // [256][NEXP]
{
    __shared__ unsigned int cnt[NEXP];
    const int lane = threadIdx.x;
    const int t = blockIdx.x * 64 + lane;
    cnt[lane] = 0u;
    __syncthreads();

    float z[NEXP];
    #pragma unroll
    for (int c = 0; c < 16; c++) {
        float4 v = *(const float4*)&part[(size_t)t * NEXP + c * 4];
        z[c*4+0] = v.x; z[c*4+1] = v.y; z[c*4+2] = v.z; z[c*4+3] = v.w;
    }
    #pragma unroll
    for (int p = 1; p < KSPLIT; p++) {
        #pragma unroll
        for (int c = 0; c < 16; c++) {
            float4 v = *(const float4*)&part[((size_t)p * NTOK + t) * NEXP + c * 4];
            z[c*4+0] += v.x; z[c*4+1] += v.y; z[c*4+2] += v.z; z[c*4+3] += v.w;
        }
    }
    float eb[NEXP];
    #pragma unroll
    for (int e = 0; e < NEXP; e++) {
        z[e] += gbias[e];
        eb[e] = ebias[e];
    }

    unsigned long long used = 0ull;
    int idxs[TOPK]; float probs[TOPK]; float psum = 0.f;
    #pragma unroll
    for (int r = 0; r < TOPK; r++) {
        float bv = -INFINITY, bz = 0.f; int bi = 0;
        #pragma unroll
        for (int e = 0; e < NEXP; e++) {
            float v = ((used >> e) & 1ull) ? -INFINITY : (z[e] + eb[e]);
            if (v > bv) { bv = v; bz = z[e]; bi = e; }
        }
        used |= 1ull << bi;
        idxs[r] = bi;
        float p = 1.f / (1.f + expf(-bz));
        probs[r] = p; psum += p;
    }
    float inv = 1.f / psum;

    float4 i0 = {(float)idxs[0], (float)idxs[1], (float)idxs[2], (float)idxs[3]};
    float4 i1 = {(float)idxs[4], (float)idxs[5], (float)idxs[6], (float)idxs[7]};
    float4 p0 = {probs[0]*inv, probs[1]*inv, probs[2]*inv, probs[3]*inv};
    float4 p1 = {probs[4]*inv, probs[5]*inv, probs[6]*inv, probs[7]*inv};
    *(float4*)&out[(size_t)t * TOPK + 0] = i0;
    *(float4*)&out[(size_t)t * TOPK + 4] = i1;
    *(float4*)&out[(size_t)NTOK * TOPK + (size_t)t * TOPK + 0] = p0;
    *(float4*)&out[(size_t)NTOK * TOPK + (size_t)t * TOPK + 4] = p1;

    if (mask[t] != 0) {
        #pragma unroll
        for (int r = 0; r < TOPK; r++) atomicAdd(&cnt[idxs[r]], 1u);
    }
    __syncthreads();
    blockcnt[(size_t)blockIdx.x * NEXP + lane] = (float)cnt[lane];
}

// ============================================================================
// Kernel 4: tree-sum per-block counts -> maxvio. One block, 256 threads.
// ============================================================================
__global__ __launch_bounds__(256) void finalize_kernel(
    const float* __restrict__ blockcnt, float* __restrict__ out)
{
    __shared__ float ps[4][NEXP];
    const int t = threadIdx.x;
    const int e = t & 63, c = t >> 6;
    float s = 0.f;
    #pragma unroll 8
    for (int b = 0; b < 64; b++)
        s += blockcnt[(size_t)(c * 64 + b) * NEXP + e];
    ps[c][e] = s;
    __syncthreads();
    if (t < 64) {
        float tot = ps[0][t] + ps[1][t] + ps[2][t] + ps[3][t];
        float mx = tot, sm = tot;
        #pragma unroll
        for (int o = 32; o > 0; o >>= 1) {
            mx = fmaxf(mx, __shfl_down(mx, o));
            sm += __shfl_down(sm, o);
        }
        if (t == 0) {
            float avg = sm / (float)NEXP;
            out[2 * NTOK * TOPK] = (mx - avg) / (avg + 1e-5f);
        }
    }
}

// ============================================================================
// Fallback for tiny workspace: R1 fused kernel (known-correct) + atomic counts.
// ============================================================================
__global__ __launch_bounds__(256) void fused_fallback_kernel(
    const float* __restrict__ x, const int* __restrict__ mask,
    const float* __restrict__ W, const float* __restrict__ gbias,
    const float* __restrict__ ebias, float* __restrict__ out,
    unsigned int* __restrict__ counts)
{
    __shared__ float As[64][36];
    __shared__ float Bs[64][36];
    __shared__ float Lg[64][NEXP + 1];
    __shared__ float s_gb[NEXP], s_eb[NEXP];
    __shared__ unsigned int s_cnt[NEXP];
    const int tid = threadIdx.x;
    const int tx = tid & 15, ty = tid >> 4;
    const int m0 = blockIdx.x * 64;
    if (tid < NEXP) { s_gb[tid] = gbias[tid]; s_eb[tid] = ebias[tid]; s_cnt[tid] = 0u; }
    float acc[4][4] = {};
    for (int kb = 0; kb < CDIM; kb += 32) {
        __syncthreads();
        #pragma unroll
        for (int p = 0; p < 2; p++) {
            int lin = tid + p * 256; int m = lin >> 3; int c4 = (lin & 7) << 2;
            *(float4*)&As[m][c4] = *(const float4*)&x[(size_t)(m0 + m) * CDIM + kb + c4];
            *(float4*)&Bs[m][c4] = *(const float4*)&W[(size_t)m * CDIM + kb + c4];
        }
        __syncthreads();
        #pragma unroll
        for (int k4 = 0; k4 < 32; k4 += 4) {
            float4 a[4], b[4];
            #pragma unroll
            for (int i = 0; i < 4; i++) a[i] = *(const float4*)&As[ty * 4 + i][k4];
            #pragma unroll
            for (int j = 0; j < 4; j++) b[j] = *(const float4*)&Bs[tx * 4 + j][k4];
            #pragma unroll
            for (int i = 0; i < 4; i++)
                #pragma unroll
                for (int j = 0; j < 4; j++)
                    acc[i][j] += a[i].x * b[j].x + a[i].y * b[j].y
                               + a[i].z * b[j].z + a[i].w * b[j].w;
        }
    }
    __syncthreads();
    #pragma unroll
    for (int i = 0; i < 4; i++)
        #pragma unroll
        for (int j = 0; j < 4; j++)
            Lg[ty * 4 + i][tx * 4 + j] = acc[i][j] + s_gb[tx * 4 + j];
    __syncthreads();
    if (tid < 64) {
        const int g = m0 + tid;
        unsigned long long used = 0ull;
        int idxs[TOPK]; float probs[TOPK]; float psum = 0.f;
        #pragma unroll
        for (int k = 0; k < TOPK; k++) {
            float best = -INFINITY; int bi = 0;
            for (int n = 0; n < NEXP; n++) {
                if ((used >> n) & 1ull) continue;
                float vv = Lg[tid][n] + s_eb[n];
                if (vv > best) { best = vv; bi = n; }
            }
            used |= (1ull << bi);
            idxs[k] = bi;
            float p = 1.f / (1.f + expf(-Lg[tid][bi]));
            probs[k] = p; psum += p;
        }
        float inv = 1.f / psum;
        #pragma unroll
        for (int k = 0; k < TOPK; k++) {
            out[(size_t)g * TOPK + k] = (float)idxs[k];
            out[(size_t)NTOK * TOPK + (size_t)g * TOPK + k] = probs[k] * inv;
        }
        if (mask[g] != 0)
            #pragma unroll
            for (int k = 0; k < TOPK; k++) atomicAdd(&s_cnt[idxs[k]], 1u);
    }
    __syncthreads();
    if (tid < NEXP && s_cnt[tid] != 0u) atomicAdd(&counts[tid], s_cnt[tid]);
}

__global__ void finalize_atomic_kernel(const unsigned int* __restrict__ counts,
                                       float* __restrict__ out)
{
    const int t = threadIdx.x;
    float c  = (float)counts[t];
    float mx = c, sm = c;
    #pragma unroll
    for (int o = 32; o > 0; o >>= 1) {
        mx = fmaxf(mx, __shfl_down(mx, o));
        sm += __shfl_down(sm, o);
    }
    if (t == 0) {
        float avg = sm / (float)NEXP;
        out[2 * NTOK * TOPK] = (mx - avg) / (avg + 1e-5f);
    }
}

extern "C" void kernel_launch(void* const* d_in, const int* in_sizes, int n_in,
                              void* d_out, int out_size, void* d_ws, size_t ws_size,
                              hipStream_t stream)
{
    const float* x     = (const float*)d_in[0];
    const int*   mask  = (const int*)  d_in[1];
    const float* W     = (const float*)d_in[2];
    const float* gbias = (const float*)d_in[3];
    const float* ebias = (const float*)d_in[4];
    float* out = (float*)d_out;

    // ws layout: [Wh 256KB][Wl 256KB][blockcnt 64KB][part 16MB]
    const size_t whB  = (size_t)NEXP * CDIM * sizeof(_Float16);       // 256 KB
    const size_t bcB  = (size_t)256 * NEXP * sizeof(float);           // 64 KB
    const size_t ptB  = (size_t)KSPLIT * NTOK * NEXP * sizeof(float); // 16 MB
    const size_t need = 2 * whB + bcB + ptB;

    if (ws_size >= need) {
        _Float16* Wh = (_Float16*)d_ws;
        _Float16* Wl = (_Float16*)((char*)d_ws + whB);
        float* blockcnt = (float*)((char*)d_ws + 2 * whB);
        float* part = (float*)((char*)d_ws + 2 * whB + bcB);

        pack_w16_kernel<<<64, 256, 0, stream>>>(W, Wh, Wl);
        gemm_f16split_kernel<<<256 * KSPLIT, 256, 0, stream>>>(x, Wh, Wl, part);
        reduce_topk_kernel<<<256, 64, 0, stream>>>(part, mask, gbias, ebias, out, blockcnt);
        finalize_kernel<<<1, 256, 0, stream>>>(blockcnt, out);
        return;
    }

    // Fallback: fused fp32 kernel + global-atomic counts
    unsigned int* counts = (unsigned int*)d_ws;
    hipMemsetAsync(d_ws, 0, NEXP * sizeof(unsigned int), stream);
    fused_fallback_kernel<<<NTOK / 64, 256, 0, stream>>>(x, mask, W, gbias, ebias, out, counts);
    finalize_atomic_kernel<<<1, 64, 0, stream>>>(counts, out);
}